// Round 12
// baseline (235.044 us; speedup 1.0000x reference)
//
#include <hip/hip_runtime.h>
#include <hip/hip_bf16.h>
#include <math.h>

// Problem constants
#define BATCH 32
#define CIN   256
#define HIN   28
#define WIN   28
#define NPROT 1024
#define HOUT  26
#define WOUT  26
#define MTOT  (BATCH*HOUT*WOUT)   // 21632 = 169*128
#define HWIN  (HIN*WIN)           // 784
#define KTOT  (CIN*9)             // 2304
#define NKT   18                  // K-tiles of 128 fp8: 9 taps x 2 halves

typedef __attribute__((ext_vector_type(8))) int   i32x8;
typedef __attribute__((ext_vector_type(4))) int   i32x4;
typedef __attribute__((ext_vector_type(4))) float f32x4;

// ---- workspace layout (bytes), fp8 operands ----
#define OFF_XT  ((size_t)0)
#define OFF_PTT ((size_t)6422528)
#define OFF_S   ((size_t)8781824)
#define OFF_PSQ ((size_t)8882176)
#define WS_NEED ((size_t)8886272)

__device__ __forceinline__ void gload16(const void* g, void* l) {
    __builtin_amdgcn_global_load_lds((__attribute__((address_space(1))) void*)g,
                                     (__attribute__((address_space(3))) void*)l,
                                     16, 0, 0);
}

// ---- P1+P2 merged: one launch. (unchanged since round 8)
__global__ __launch_bounds__(256)
void prep_kernel(const float* __restrict__ x, const float* __restrict__ proto,
                 unsigned char* __restrict__ xT, unsigned char* __restrict__ pTT,
                 float* __restrict__ s, float* __restrict__ psq) {
    const int bid = blockIdx.x;
    if (bid < 800) {
        __shared__ float tile[32 * 256];          // 32 KB
        __shared__ float red[32][33];
        __shared__ float red2[8][33];
        const int tid = threadIdx.x;
        const int b = bid / 25, hw0 = (bid % 25) * 32;
        const int i = tid & 7, cr = tid >> 3;
        const float* xb = x + (size_t)b * CIN * HWIN;
        const bool full = (hw0 + 32 <= HWIN);
        float sq[4] = {0.f, 0.f, 0.f, 0.f};
#pragma unroll
        for (int q = 0; q < 8; ++q) {
            const int c = q * 32 + cr;
            const int hw = hw0 + i * 4;
            float4 v;
            if (full) {
                v = *(const float4*)&xb[(size_t)c * HWIN + hw];
            } else {
                v.x = (hw + 0 < HWIN) ? xb[(size_t)c * HWIN + hw + 0] : 0.f;
                v.y = (hw + 1 < HWIN) ? xb[(size_t)c * HWIN + hw + 1] : 0.f;
                v.z = (hw + 2 < HWIN) ? xb[(size_t)c * HWIN + hw + 2] : 0.f;
                v.w = (hw + 3 < HWIN) ? xb[(size_t)c * HWIN + hw + 3] : 0.f;
            }
            const int cq = (c >> 3), c7 = c & 7;
            float vv[4] = {v.x, v.y, v.z, v.w};
#pragma unroll
            for (int d = 0; d < 4; ++d) {
                const int hwl = i * 4 + d;
                const int rot = ((hwl >> 2) | (hwl << 3)) & 31;
                tile[hwl * 256 + ((cq ^ rot) << 3) + c7] = vv[d];
                sq[d] += vv[d] * vv[d];
            }
        }
#pragma unroll
        for (int d = 0; d < 4; ++d) red[cr][i * 4 + d] = sq[d];
        __syncthreads();

        const int v2 = tid & 31, u = tid >> 5;
        {
            float part = 0.f;
#pragma unroll
            for (int j = 0; j < 4; ++j) part += red[u + 8 * j][v2];
            red2[u][v2] = part;
        }
#pragma unroll
        for (int w = 0; w < 4; ++w) {
            const int hwl = w * 8 + u;
            const int hw = hw0 + hwl;
            if (hw < HWIN) {
                const int rot = ((hwl >> 2) | (hwl << 3)) & 31;
                const float* g = &tile[hwl * 256 + ((v2 ^ rot) << 3)];
                float fa[8];
                *(float4*)&fa[0] = *(const float4*)g;
                *(float4*)&fa[4] = *(const float4*)(g + 4);
                int d0 = __builtin_amdgcn_cvt_pk_fp8_f32(fa[0], fa[1], 0, 0);
                d0     = __builtin_amdgcn_cvt_pk_fp8_f32(fa[2], fa[3], d0, 1);
                int d1 = __builtin_amdgcn_cvt_pk_fp8_f32(fa[4], fa[5], 0, 0);
                d1     = __builtin_amdgcn_cvt_pk_fp8_f32(fa[6], fa[7], d1, 1);
                int2 o; o.x = d0; o.y = d1;
                *(int2*)&xT[((size_t)b * HWIN + hw) * CIN + v2 * 8] = o;
            }
        }
        __syncthreads();
        if (u == 0) {
            const int hw = hw0 + v2;
            if (hw < HWIN) {
                float a = 0.f;
#pragma unroll
                for (int k = 0; k < 8; ++k) a += red2[k][v2];
                s[b * HWIN + hw] = a;
            }
        }
    } else {
        const int p = bid - 800, c = threadIdx.x;
        const float* pp = proto + ((size_t)p * CIN + c) * 9;
        float v[9]; float ss = 0.f;
#pragma unroll
        for (int t = 0; t < 9; ++t) { v[t] = pp[t]; ss += v[t] * v[t]; }
#pragma unroll
        for (int t = 0; t < 9; ++t) {
            int q8 = __builtin_amdgcn_cvt_pk_fp8_f32(v[t], 0.f, 0, 0);
            pTT[((size_t)t * NPROT + p) * CIN + c] = (unsigned char)(q8 & 0xff);
        }
        for (int o = 32; o > 0; o >>= 1) ss += __shfl_down(ss, o, 64);
        __shared__ float redp[4];
        if ((c & 63) == 0) redp[c >> 6] = ss;
        __syncthreads();
        if (c == 0) psq[p] = redp[0] + redp[1] + redp[2] + redp[3];
    }
}

// ---- G: implicit-GEMM MX-fp8 MFMA (16x16x128, scales=1.0).
// Round-12 delta: SINGLE 32KB buffer + m97 2-barrier schedule -> 33.8KB LDS
// -> 4 blocks/CU (vs 2), VGPR held <=128 by __launch_bounds__(256,4) with
// no squeeze (was 120). Rationale: pipe accounting shows MFMA 22us + LDS
// 46us busy inside a 98us wall -- half the kernel is barrier/latency stall,
// and the stall-filler at this structure is co-resident blocks (m114).
// R1's occupancy attempt failed because it squeezed VGPRs WITHOUT freeing
// LDS; this frees LDS. Per-tile exposed load latency grows (drain after
// issue) but 4 sibling blocks fill it (m97's mechanism, 37% MfmaUtil).
// Everything verified stays byte-identical: granule-permuted zero-conflict
// LDS layout (R10), fragment math (R9), s3/psq epilogue tables (R11).
__global__ __launch_bounds__(256, 4)
void gemm_kernel(const unsigned char* __restrict__ xT,
                 const unsigned char* __restrict__ pTT,
                 const float* __restrict__ s,
                 const float* __restrict__ psq,
                 float* __restrict__ out) {
    __shared__ unsigned char lds[32768];   // [ A:0..16383 | B:16384..32767 ]
    __shared__ float s3t[128];             // 3x3 box of s for this m-tile
    __shared__ float psqt[128];            // psq for this p-tile
    const int tid = threadIdx.x, wave = tid >> 6, lane = tid & 63;
    const int n0 = blockIdx.x * 128;  // m (image-pos) tile base
    const int m0 = blockIdx.y * 128;  // p tile base
    const int lrow = lane >> 3;
    // granule permute: slot t holds granule rho^-1(t ^ (row&7)),
    // rho(2q)=q, rho(2q+1)=q+4; read slots match R3's measured-zero family.
    const int tkey = (lane & 7) ^ lrow;
    const int gsrc = ((tkey & 3) << 1) | ((tkey >> 2) & 1);
    const int lcol = gsrc * 16;                 // source byte offset in row

    int xbase[4], pbase[4];
#pragma unroll
    for (int q = 0; q < 4; ++q) {
        int rl = wave * 32 + q * 8 + lrow;
        int mm = n0 + rl;
        int bb = mm / 676, rr = mm % 676, ii = rr / WOUT, jj = rr % WOUT;
        xbase[q] = (bb * HWIN + ii * WIN + jj) * CIN + lcol;
        pbase[q] = (m0 + rl) * CIN + lcol;
    }

    // stage K-tile kt (128 fp8 k-elts): 8 gloads per wave, single buffer
    auto stage = [&](int kt) {
        const int tap = kt >> 1, cc = (kt & 1) * 128;
        const unsigned char* srcP = pTT + (size_t)tap * (NPROT * CIN) + cc;
        const unsigned char* srcX = xT + ((tap / 3) * WIN + (tap % 3)) * CIN + cc;
#pragma unroll
        for (int q = 0; q < 4; ++q) {
            gload16(srcP + pbase[q], lds + (wave * 32 + q * 8) * 128);
            gload16(srcX + xbase[q], lds + 16384 + (wave * 32 + q * 8) * 128);
        }
    };

    f32x4 acc[4][4];
#pragma unroll
    for (int a = 0; a < 4; ++a)
#pragma unroll
        for (int b = 0; b < 4; ++b) acc[a][b] = (f32x4){0.f, 0.f, 0.f, 0.f};

    const int wr = wave >> 1, wc = wave & 1;   // wave 2x2: wr->p dir, wc->m dir
    const int quad = lane >> 4, l15 = lane & 15;
    const int sw = l15 & 7;                    // row&7 (row bases are %8==0)
    const int c0 = quad ^ sw, c1 = c0 ^ 4;     // measured-zero slot family

    // epilogue tables, written once; the loop's barriers order them.
    if (tid < 128) {
        int mm = n0 + tid;
        int bb = mm / 676, rr = mm % 676, ii = rr / WOUT, jj = rr % WOUT;
        const float* sb = s + bb * HWIN + ii * WIN + jj;
        float v = 0.f;
#pragma unroll
        for (int di = 0; di < 3; ++di)
#pragma unroll
            for (int dj = 0; dj < 3; ++dj) v += sb[di * WIN + dj];
        s3t[tid] = v;
        psqt[tid] = psq[m0 + tid];
    }

#pragma unroll 2
    for (int kt = 0; kt < NKT; ++kt) {
        // stage -> drain -> barrier (m97): siblings cover the drain.
        stage(kt);
        asm volatile("s_waitcnt vmcnt(0)" ::: "memory");
        __builtin_amdgcn_s_barrier();

        const unsigned char* A = lds;
        const unsigned char* B = lds + 16384;
        i32x8 af[4], bf[4];
#pragma unroll
        for (int im = 0; im < 4; ++im) {
            const int rb = (wr * 64 + im * 16 + l15) * 128;
            i32x4 lo = *(const i32x4*)&A[rb + c0 * 16];
            i32x4 hi = *(const i32x4*)&A[rb + c1 * 16];
            af[im] = __builtin_shufflevector(lo, hi, 0, 1, 2, 3, 4, 5, 6, 7);
        }
#pragma unroll
        for (int in = 0; in < 4; ++in) {
            const int rb = (wc * 64 + in * 16 + l15) * 128;
            i32x4 lo = *(const i32x4*)&B[rb + c0 * 16];
            i32x4 hi = *(const i32x4*)&B[rb + c1 * 16];
            bf[in] = __builtin_shufflevector(lo, hi, 0, 1, 2, 3, 4, 5, 6, 7);
        }
#pragma unroll
        for (int im = 0; im < 4; ++im)
#pragma unroll
            for (int in = 0; in < 4; ++in)
                acc[im][in] = __builtin_amdgcn_mfma_scale_f32_16x16x128_f8f6f4(
                    af[im], bf[in], acc[im][in],
                    0 /*A=fp8 e4m3*/, 0 /*B=fp8 e4m3*/,
                    0, 127, 0, 127 /*scales = 2^0*/);

        // all reads of this tile retired (lgkmcnt waits precede the MFMAs);
        // barrier before the next overwrite.
        __builtin_amdgcn_s_barrier();
    }

    // epilogue: out[b][p][i][j] = sqrt(clip(s3 - 2C + psq)); s3/psq from LDS
#pragma unroll
    for (int in = 0; in < 4; ++in) {
        const int ml = wc * 64 + in * 16 + l15;
        int mm = n0 + ml;
        int bb = mm / 676, rr = mm % 676;
        float s3v = s3t[ml];
        float* ob = out + (size_t)bb * (NPROT * 676) + rr;
#pragma unroll
        for (int im = 0; im < 4; ++im) {
            int pl = wr * 64 + im * 16 + quad * 4;
#pragma unroll
            for (int r = 0; r < 4; ++r) {
                float d2 = s3v - 2.f * acc[im][in][r] + psqt[pl + r];
                ob[(size_t)(m0 + pl + r) * 676] = sqrtf(fmaxf(d2, 1e-14f));
            }
        }
    }
}

// ---- fallback (only if ws too small): direct fp32 ----
__global__ void naive_kernel(const float* __restrict__ x,
                             const float* __restrict__ proto,
                             float* __restrict__ out) {
    __shared__ float patch[KTOT];
    int m = blockIdx.x;
    int b = m / 676, rr = m % 676, i = rr / WOUT, j = rr % WOUT;
    int c = threadIdx.x;
    const float* xb = x + (((size_t)b * CIN + c) * HIN + i) * WIN + j;
    for (int t = 0; t < 9; ++t) patch[c * 9 + t] = xb[(t / 3) * WIN + (t % 3)];
    __syncthreads();
    for (int pp = threadIdx.x; pp < NPROT; pp += 256) {
        const float* pr = proto + (size_t)pp * KTOT;
        float acc = 0.f;
        for (int k = 0; k < KTOT; ++k) { float d = patch[k] - pr[k]; acc += d * d; }
        out[((size_t)b * NPROT + pp) * 676 + rr] = sqrtf(fmaxf(acc, 1e-14f));
    }
}

extern "C" void kernel_launch(void* const* d_in, const int* in_sizes, int n_in,
                              void* d_out, int out_size, void* d_ws, size_t ws_size,
                              hipStream_t stream) {
    const float* x = (const float*)d_in[0];
    const float* proto = (const float*)d_in[1];
    float* out = (float*)d_out;

    if (ws_size < WS_NEED) {
        naive_kernel<<<MTOT, 256, 0, stream>>>(x, proto, out);
        return;
    }

    char* ws = (char*)d_ws;
    unsigned char* xT  = (unsigned char*)(ws + OFF_XT);
    unsigned char* pTT = (unsigned char*)(ws + OFF_PTT);
    float* s   = (float*)(ws + OFF_S);
    float* psq = (float*)(ws + OFF_PSQ);

    prep_kernel<<<dim3(800 + NPROT), 256, 0, stream>>>(x, proto, xT, pTT, s, psq);
    gemm_kernel<<<dim3(169, 8), 256, 0, stream>>>(xT, pTT, s, psq, out);
}

// Round 13
// 192.475 us; speedup vs baseline: 1.2212x; 1.2212x over previous
//
#include <hip/hip_runtime.h>
#include <hip/hip_bf16.h>
#include <math.h>

// Problem constants
#define BATCH 32
#define CIN   256
#define HIN   28
#define WIN   28
#define NPROT 1024
#define HOUT  26
#define WOUT  26
#define MTOT  (BATCH*HOUT*WOUT)   // 21632 = 169*128
#define HWIN  (HIN*WIN)           // 784
#define KTOT  (CIN*9)             // 2304
#define NKT   18                  // K-tiles of 128 fp8: 9 taps x 2 halves

typedef __attribute__((ext_vector_type(8))) int   i32x8;
typedef __attribute__((ext_vector_type(4))) int   i32x4;
typedef __attribute__((ext_vector_type(4))) float f32x4;

// ---- workspace layout (bytes), fp8 operands ----
#define OFF_XT  ((size_t)0)
#define OFF_PTT ((size_t)6422528)
#define OFF_S   ((size_t)8781824)
#define OFF_PSQ ((size_t)8882176)
#define WS_NEED ((size_t)8886272)

__device__ __forceinline__ void gload16(const void* g, void* l) {
    __builtin_amdgcn_global_load_lds((__attribute__((address_space(1))) void*)g,
                                     (__attribute__((address_space(3))) void*)l,
                                     16, 0, 0);
}

// ---- P1+P2 merged: one launch. (unchanged since round 8)
__global__ __launch_bounds__(256)
void prep_kernel(const float* __restrict__ x, const float* __restrict__ proto,
                 unsigned char* __restrict__ xT, unsigned char* __restrict__ pTT,
                 float* __restrict__ s, float* __restrict__ psq) {
    const int bid = blockIdx.x;
    if (bid < 800) {
        __shared__ float tile[32 * 256];          // 32 KB
        __shared__ float red[32][33];
        __shared__ float red2[8][33];
        const int tid = threadIdx.x;
        const int b = bid / 25, hw0 = (bid % 25) * 32;
        const int i = tid & 7, cr = tid >> 3;
        const float* xb = x + (size_t)b * CIN * HWIN;
        const bool full = (hw0 + 32 <= HWIN);
        float sq[4] = {0.f, 0.f, 0.f, 0.f};
#pragma unroll
        for (int q = 0; q < 8; ++q) {
            const int c = q * 32 + cr;
            const int hw = hw0 + i * 4;
            float4 v;
            if (full) {
                v = *(const float4*)&xb[(size_t)c * HWIN + hw];
            } else {
                v.x = (hw + 0 < HWIN) ? xb[(size_t)c * HWIN + hw + 0] : 0.f;
                v.y = (hw + 1 < HWIN) ? xb[(size_t)c * HWIN + hw + 1] : 0.f;
                v.z = (hw + 2 < HWIN) ? xb[(size_t)c * HWIN + hw + 2] : 0.f;
                v.w = (hw + 3 < HWIN) ? xb[(size_t)c * HWIN + hw + 3] : 0.f;
            }
            const int cq = (c >> 3), c7 = c & 7;
            float vv[4] = {v.x, v.y, v.z, v.w};
#pragma unroll
            for (int d = 0; d < 4; ++d) {
                const int hwl = i * 4 + d;
                const int rot = ((hwl >> 2) | (hwl << 3)) & 31;
                tile[hwl * 256 + ((cq ^ rot) << 3) + c7] = vv[d];
                sq[d] += vv[d] * vv[d];
            }
        }
#pragma unroll
        for (int d = 0; d < 4; ++d) red[cr][i * 4 + d] = sq[d];
        __syncthreads();

        const int v2 = tid & 31, u = tid >> 5;
        {
            float part = 0.f;
#pragma unroll
            for (int j = 0; j < 4; ++j) part += red[u + 8 * j][v2];
            red2[u][v2] = part;
        }
#pragma unroll
        for (int w = 0; w < 4; ++w) {
            const int hwl = w * 8 + u;
            const int hw = hw0 + hwl;
            if (hw < HWIN) {
                const int rot = ((hwl >> 2) | (hwl << 3)) & 31;
                const float* g = &tile[hwl * 256 + ((v2 ^ rot) << 3)];
                float fa[8];
                *(float4*)&fa[0] = *(const float4*)g;
                *(float4*)&fa[4] = *(const float4*)(g + 4);
                int d0 = __builtin_amdgcn_cvt_pk_fp8_f32(fa[0], fa[1], 0, 0);
                d0     = __builtin_amdgcn_cvt_pk_fp8_f32(fa[2], fa[3], d0, 1);
                int d1 = __builtin_amdgcn_cvt_pk_fp8_f32(fa[4], fa[5], 0, 0);
                d1     = __builtin_amdgcn_cvt_pk_fp8_f32(fa[6], fa[7], d1, 1);
                int2 o; o.x = d0; o.y = d1;
                *(int2*)&xT[((size_t)b * HWIN + hw) * CIN + v2 * 8] = o;
            }
        }
        __syncthreads();
        if (u == 0) {
            const int hw = hw0 + v2;
            if (hw < HWIN) {
                float a = 0.f;
#pragma unroll
                for (int k = 0; k < 8; ++k) a += red2[k][v2];
                s[b * HWIN + hw] = a;
            }
        }
    } else {
        const int p = bid - 800, c = threadIdx.x;
        const float* pp = proto + ((size_t)p * CIN + c) * 9;
        float v[9]; float ss = 0.f;
#pragma unroll
        for (int t = 0; t < 9; ++t) { v[t] = pp[t]; ss += v[t] * v[t]; }
#pragma unroll
        for (int t = 0; t < 9; ++t) {
            int q8 = __builtin_amdgcn_cvt_pk_fp8_f32(v[t], 0.f, 0, 0);
            pTT[((size_t)t * NPROT + p) * CIN + c] = (unsigned char)(q8 & 0xff);
        }
        for (int o = 32; o > 0; o >>= 1) ss += __shfl_down(ss, o, 64);
        __shared__ float redp[4];
        if ((c & 63) == 0) redp[c >> 6] = ss;
        __syncthreads();
        if (c == 0) psq[p] = redp[0] + redp[1] + redp[2] + redp[3];
    }
}

// ---- G: implicit-GEMM MX-fp8 MFMA (16x16x128, scales=1.0), 2-deep
// issue-early pipeline, granule-permuted LDS. This is the measured-best
// configuration (R10: gemm 98.4us, SQ_LDS_BANK_CONFLICT==0, total 192.6us),
// reverted to verbatim after R12 falsified the occupancy lever:
//  - 2 blocks/CU is the L2-RESIDENCY optimum: at ~2.7 blocks/CU (R12) the
//    per-XCD working set overflows the 4MB L2 (FETCH 40->234MB) and every
//    staging load becomes a ~900cy HBM miss -- more waves, 4.5x the latency.
//  - counted-vmcnt deeper pipelines (R2/R4/R7) all lost to this simple
//    issue-early/drain-late schedule at this problem size (18 K-tiles).
//  - granule permute: slot t holds granule rho^-1(t ^ (row&7)), rho(2q)=q,
//    rho(2q+1)=q+4; read slots quad^sw / (quad^4)^sw are the only measured
//    zero-conflict family (validated R3/R6/R10 vs R4/R5/R7/R9 4-way).
__global__ __launch_bounds__(256, 2)
void gemm_kernel(const unsigned char* __restrict__ xT,
                 const unsigned char* __restrict__ pTT,
                 const float* __restrict__ s,
                 const float* __restrict__ psq,
                 float* __restrict__ out) {
    __shared__ unsigned char lds[2][32768];  // [buf][ A:0..16383 | B:16384..32767 ]
    const int tid = threadIdx.x, wave = tid >> 6, lane = tid & 63;
    const int n0 = blockIdx.x * 128;  // m (image-pos) tile base
    const int m0 = blockIdx.y * 128;  // p tile base
    const int lrow = lane >> 3;
    const int tkey = (lane & 7) ^ lrow;
    const int gsrc = ((tkey & 3) << 1) | ((tkey >> 2) & 1);
    const int lcol = gsrc * 16;                 // source byte offset in row

    int xbase[4], pbase[4];
#pragma unroll
    for (int q = 0; q < 4; ++q) {
        int rl = wave * 32 + q * 8 + lrow;
        int mm = n0 + rl;
        int bb = mm / 676, rr = mm % 676, ii = rr / WOUT, jj = rr % WOUT;
        xbase[q] = (bb * HWIN + ii * WIN + jj) * CIN + lcol;
        pbase[q] = (m0 + rl) * CIN + lcol;
    }

    // stage K-tile kt (128 fp8 k-elts) into buffer buf: 8 gloads per wave
    auto stage = [&](int kt, int buf) {
        const int tap = kt >> 1, cc = (kt & 1) * 128;
        const unsigned char* srcP = pTT + (size_t)tap * (NPROT * CIN) + cc;
        const unsigned char* srcX = xT + ((tap / 3) * WIN + (tap % 3)) * CIN + cc;
        unsigned char* base = &lds[buf][0];
#pragma unroll
        for (int q = 0; q < 4; ++q) {
            gload16(srcP + pbase[q], base + (wave * 32 + q * 8) * 128);
            gload16(srcX + xbase[q], base + 16384 + (wave * 32 + q * 8) * 128);
        }
    };

    f32x4 acc[4][4];
#pragma unroll
    for (int a = 0; a < 4; ++a)
#pragma unroll
        for (int b = 0; b < 4; ++b) acc[a][b] = (f32x4){0.f, 0.f, 0.f, 0.f};

    const int wr = wave >> 1, wc = wave & 1;   // wave 2x2: wr->p dir, wc->m dir
    const int quad = lane >> 4, l15 = lane & 15;
    const int sw = l15 & 7;                    // row&7 (row bases are %8==0)
    const int c0 = quad ^ sw, c1 = c0 ^ 4;     // measured-zero slot family

    stage(0, 0);
    asm volatile("s_waitcnt vmcnt(0)" ::: "memory");
    __builtin_amdgcn_s_barrier();

#pragma unroll 2
    for (int kt = 0; kt < NKT; ++kt) {
        const int cur = kt & 1;
        const bool st = (kt + 1) < NKT;
        if (st) stage(kt + 1, cur ^ 1);      // issue next tile's loads FIRST

        const unsigned char* A = &lds[cur][0];
        const unsigned char* B = &lds[cur][16384];
        i32x8 af[4], bf[4];
#pragma unroll
        for (int im = 0; im < 4; ++im) {
            const int rb = (wr * 64 + im * 16 + l15) * 128;
            i32x4 lo = *(const i32x4*)&A[rb + c0 * 16];
            i32x4 hi = *(const i32x4*)&A[rb + c1 * 16];
            af[im][0] = lo[0]; af[im][1] = lo[1]; af[im][2] = lo[2]; af[im][3] = lo[3];
            af[im][4] = hi[0]; af[im][5] = hi[1]; af[im][6] = hi[2]; af[im][7] = hi[3];
        }
#pragma unroll
        for (int in = 0; in < 4; ++in) {
            const int rb = (wc * 64 + in * 16 + l15) * 128;
            i32x4 lo = *(const i32x4*)&B[rb + c0 * 16];
            i32x4 hi = *(const i32x4*)&B[rb + c1 * 16];
            bf[in][0] = lo[0]; bf[in][1] = lo[1]; bf[in][2] = lo[2]; bf[in][3] = lo[3];
            bf[in][4] = hi[0]; bf[in][5] = hi[1]; bf[in][6] = hi[2]; bf[in][7] = hi[3];
        }
#pragma unroll
        for (int im = 0; im < 4; ++im)
#pragma unroll
            for (int in = 0; in < 4; ++in)
                acc[im][in] = __builtin_amdgcn_mfma_scale_f32_16x16x128_f8f6f4(
                    af[im], bf[in], acc[im][in],
                    0 /*cbsz: A=fp8 e4m3*/, 0 /*blgp: B=fp8 e4m3*/,
                    0, 127 /*scale A = 2^0*/, 0, 127 /*scale B = 2^0*/);

        if (st) {
            asm volatile("s_waitcnt vmcnt(0)" ::: "memory");
            __builtin_amdgcn_s_barrier();
        }
    }

    // epilogue: out[b][p][i][j] = sqrt(clip(s3 - 2C + psq)), s3 = 3x3 box of s
#pragma unroll
    for (int in = 0; in < 4; ++in) {
        int mm = n0 + wc * 64 + in * 16 + l15;
        int bb = mm / 676, rr = mm % 676, ii = rr / WOUT, jj = rr % WOUT;
        const float* sb = s + bb * HWIN + ii * WIN + jj;
        float s3v = 0.f;
#pragma unroll
        for (int di = 0; di < 3; ++di)
#pragma unroll
            for (int dj = 0; dj < 3; ++dj) s3v += sb[di * WIN + dj];
        float* ob = out + (size_t)bb * (NPROT * 676) + rr;
#pragma unroll
        for (int im = 0; im < 4; ++im) {
            int pbase_ = m0 + wr * 64 + im * 16 + quad * 4;
#pragma unroll
            for (int r = 0; r < 4; ++r) {
                int p = pbase_ + r;
                float d2 = s3v - 2.f * acc[im][in][r] + psq[p];
                ob[(size_t)p * 676] = sqrtf(fmaxf(d2, 1e-14f));
            }
        }
    }
}

// ---- fallback (only if ws too small): direct fp32 ----
__global__ void naive_kernel(const float* __restrict__ x,
                             const float* __restrict__ proto,
                             float* __restrict__ out) {
    __shared__ float patch[KTOT];
    int m = blockIdx.x;
    int b = m / 676, rr = m % 676, i = rr / WOUT, j = rr % WOUT;
    int c = threadIdx.x;
    const float* xb = x + (((size_t)b * CIN + c) * HIN + i) * WIN + j;
    for (int t = 0; t < 9; ++t) patch[c * 9 + t] = xb[(t / 3) * WIN + (t % 3)];
    __syncthreads();
    for (int pp = threadIdx.x; pp < NPROT; pp += 256) {
        const float* pr = proto + (size_t)pp * KTOT;
        float acc = 0.f;
        for (int k = 0; k < KTOT; ++k) { float d = patch[k] - pr[k]; acc += d * d; }
        out[((size_t)b * NPROT + pp) * 676 + rr] = sqrtf(fmaxf(acc, 1e-14f));
    }
}

extern "C" void kernel_launch(void* const* d_in, const int* in_sizes, int n_in,
                              void* d_out, int out_size, void* d_ws, size_t ws_size,
                              hipStream_t stream) {
    const float* x = (const float*)d_in[0];
    const float* proto = (const float*)d_in[1];
    float* out = (float*)d_out;

    if (ws_size < WS_NEED) {
        naive_kernel<<<MTOT, 256, 0, stream>>>(x, proto, out);
        return;
    }

    char* ws = (char*)d_ws;
    unsigned char* xT  = (unsigned char*)(ws + OFF_XT);
    unsigned char* pTT = (unsigned char*)(ws + OFF_PTT);
    float* s   = (float*)(ws + OFF_S);
    float* psq = (float*)(ws + OFF_PSQ);

    prep_kernel<<<dim3(800 + NPROT), 256, 0, stream>>>(x, proto, xT, pTT, s, psq);
    gemm_kernel<<<dim3(169, 8), 256, 0, stream>>>(xT, pTT, s, psq, out);
}